// Round 6
// baseline (419.510 us; speedup 1.0000x reference)
//
#include <hip/hip_runtime.h>
#include <hip/hip_bf16.h>
#include <stdint.h>

typedef __attribute__((ext_vector_type(8))) short s16x8;   // 8 bf16 in 4 VGPRs
typedef __attribute__((ext_vector_type(4))) float f32x4;
typedef __attribute__((ext_vector_type(2))) float f32x2;

#define AS1(p) ((const __attribute__((address_space(1))) void*)(p))
#define AS3(p) ((__attribute__((address_space(3))) void*)(p))

__device__ __forceinline__ ushort f2bf(float f){
  union { float f; uint32_t u; } v; v.f = f;
  uint32_t r = v.u + 0x7FFFu + ((v.u >> 16) & 1u);   // RNE
  return (ushort)(r >> 16);
}
__device__ __forceinline__ float bf2f(ushort u){
  union { uint32_t u; float f; } v; v.u = ((uint32_t)u) << 16; return v.f;
}
// v_exp_f32 computes 2^x. s_nop covers the TRANS->VALU consumer hazard for asm results.
__device__ __forceinline__ float exp2_fast(float x){
  float r;
  asm("v_exp_f32 %0, %1\n\ts_nop 0" : "=v"(r) : "v"(x));
  return r;
}
// packed f32x2 -> 2x bf16 (RNE), gfx950
__device__ __forceinline__ uint32_t cvt_pk_bf16(float lo, float hi){
  uint32_t r;
  asm("v_cvt_pk_bf16_f32 %0, %1, %2" : "=v"(r) : "v"(lo), "v"(hi));
  return r;
}
// K-row permutation: r -> rho so that QK^T D-rows give k = 32m+8lg+4e+t directly
__device__ __forceinline__ int rho_of(int r){
  int m = r>>5, a = (r>>3)&3, j = r&7;
  return (2*m + (j>>2))*16 + 4*a + (j&3);
}

// ---------------- 1a. LN partial sums over r-slices ----------------
__global__ __launch_bounds__(256) void ln_part(const float* __restrict__ msa,
    float* __restrict__ part){
  int s = blockIdx.x, rq = blockIdx.y, c = threadIdx.x;   // 128 x 8, 256
  const float* p = msa + (size_t)s*98304 + (size_t)rq*48*256 + c;
  float sum = 0.f, sq = 0.f;
  for (int r = 0; r < 48; ++r){ float v = p[(size_t)r*256]; sum += v; sq += v*v; }
  f32x2* o = (f32x2*)part;
  o[((size_t)s*8 + rq)*256 + c] = (f32x2){sum, sq};
}

// ---------------- 1b. LN stats ----------------
__global__ __launch_bounds__(256) void ln_stats(const float* __restrict__ part,
    float* __restrict__ stats){
  int s = blockIdx.x, c = threadIdx.x;
  const f32x2* p = (const f32x2*)part;
  float sum = 0.f, sq = 0.f;
  #pragma unroll
  for (int rq = 0; rq < 8; ++rq){
    f32x2 v = p[((size_t)s*8 + rq)*256 + c];
    sum += v.x; sq += v.y;
  }
  float mu = sum * (1.f/384.f);
  float var = sq * (1.f/384.f) - mu*mu;
  ((f32x2*)stats)[(size_t)s*256 + c] = (f32x2){mu, rsqrtf(var + 1e-5f)};
}

// ---------------- 1c. LN apply -> bf16 x ----------------
__global__ __launch_bounds__(256) void ln_apply(const float* __restrict__ msa,
    const float* __restrict__ stats, const float* __restrict__ ln_g,
    const float* __restrict__ ln_b, ushort* __restrict__ xbf){
  int s = blockIdx.x, rq = blockIdx.y, c = threadIdx.x;
  f32x2 st = ((const f32x2*)stats)[(size_t)s*256 + c];
  const float* p = msa + (size_t)s*98304 + (size_t)rq*48*256 + c;
  ushort* o = xbf + (size_t)s*98304 + (size_t)rq*48*256 + c;
  for (int r = 0; r < 48; ++r){
    int rr = rq*48 + r;
    float v = (p[(size_t)r*256] - st.x) * st.y * ln_g[rr] + ln_b[rr];
    o[(size_t)r*256] = f2bf(v);
  }
}

// ---------------- 2. convert weights to bf16, transposed Wt[n][k] ----------------
__global__ __launch_bounds__(256) void cvt_w(const float* __restrict__ Wq, const float* __restrict__ Wk,
    const float* __restrict__ Wv, const float* __restrict__ Wg, const float* __restrict__ Wo,
    ushort* __restrict__ out){
  int w = blockIdx.y;
  const float* W = (w==0)?Wq:(w==1)?Wk:(w==2)?Wv:(w==3)?Wg:Wo;
  int idx = blockIdx.x*256 + threadIdx.x;   // 0..65535
  int k = idx >> 8, n = idx & 255;
  out[(size_t)w*65536 + (size_t)n*256 + k] = f2bf(W[idx]);
}

// ---------------- 3. pair bias (pre-scaled by log2e for exp2 softmax) ----------------
__global__ __launch_bounds__(256) void bias_kernel(const float* __restrict__ pair,
    const float* __restrict__ Wb, const float* __restrict__ bb, float* __restrict__ bias){
  __shared__ float pl[32*133];
  __shared__ float wb[128*8];
  int i = blockIdx.x, j0 = blockIdx.y*32, tid = threadIdx.x;
  for (int t = tid; t < 1024; t += 256) wb[t] = Wb[t];
  const float* src = pair + ((size_t)i*384 + j0)*128;
  for (int t = tid; t < 4096; t += 256){ int j = t>>7, c = t&127; pl[j*133 + c] = src[t]; }
  __syncthreads();
  int h = tid >> 5, jj = tid & 31;
  float acc = bb[h];
  const float* row = pl + jj*133;
  #pragma unroll 8
  for (int c = 0; c < 128; ++c) acc = fmaf(row[c], wb[c*8 + h], acc);
  bias[(size_t)h*147456 + (size_t)i*384 + (j0 + jj)] = acc * 1.4426950408889634f;
}

// ---------------- LDS-staged 64-row A-tile GEMM core ----------------
__device__ __forceinline__ void stage_a64(const ushort* __restrict__ A, int m0,
                                          ushort* Al, int tid){
  int wave = tid>>6, lane = tid&63;
  #pragma unroll
  for (int it = 0; it < 8; ++it){
    int chunk = wave*8 + it;             // 32 chunks of 1 KB
    int base  = chunk*1024;              // wave-uniform LDS byte base
    int beta  = base + lane*16;          // this lane's implicit dest
    int row   = beta>>9, cbs = beta&511;
    int cb    = cbs ^ ((row&7)<<4);      // involution
    const char* src = (const char*)A + (size_t)(m0+row)*512 + cb;
    __builtin_amdgcn_global_load_lds(AS1(src), AS3((char*)Al + base), 16, 0, 0);
  }
}

__device__ __forceinline__ void gemm64_lds(const ushort* Al, const ushort* __restrict__ Bt,
                                           int lr, int lg, f32x4 acc[4][4]){
  #pragma unroll
  for (int ks = 0; ks < 8; ++ks){
    s16x8 a[4], b[4];
    #pragma unroll
    for (int mt = 0; mt < 4; ++mt){
      int row = mt*16 + lr;
      int beta = row*512 + ((ks*64 + lg*16) ^ ((lr&7)<<4));
      a[mt] = *reinterpret_cast<const s16x8*>((const char*)Al + beta);
    }
    #pragma unroll
    for (int nt = 0; nt < 4; ++nt)
      b[nt] = *reinterpret_cast<const s16x8*>(Bt + (size_t)(nt*16 + lr)*256 + ks*32 + lg*8);
    #pragma unroll
    for (int mt = 0; mt < 4; ++mt)
      #pragma unroll
      for (int nt = 0; nt < 4; ++nt)
        acc[mt][nt] = __builtin_amdgcn_mfma_f32_16x16x32_bf16(a[mt], b[nt], acc[mt][nt], 0, 0, 0);
  }
}

// ---------------- 4. projections ----------------
// q,g: [s][h][r][d].  k: rho-permuted [s][h][rho][d].  v: transposed [s][h][d][r].
__global__ __launch_bounds__(256, 4) void proj_kernel(const ushort* __restrict__ xbf,
    const ushort* __restrict__ wt_all, const float* __restrict__ bg,
    ushort* __restrict__ q, ushort* __restrict__ k, ushort* __restrict__ v, ushort* __restrict__ g){
  __shared__ ushort Al[64*256];
  int w = blockIdx.y;
  const ushort* Bt = wt_all + (size_t)w*65536;
  int tid = threadIdx.x, wave = tid>>6, lane = tid&63, lr = lane&15, lg = lane>>4;
  int m0 = blockIdx.x*64;
  stage_a64(xbf, m0, Al, tid);
  __syncthreads();
  f32x4 acc[4][4];
  #pragma unroll
  for (int a=0;a<4;++a) for (int b=0;b<4;++b) acc[a][b] = (f32x4){0.f,0.f,0.f,0.f};
  gemm64_lds(Al, Bt + (size_t)(wave*64)*256, lr, lg, acc);
  #pragma unroll
  for (int mt = 0; mt < 4; ++mt){
    int mrow = m0 + mt*16 + lg*4;        // 64-tile never straddles s (384%64==0)
    int s = mrow/384, rbase = mrow - s*384;
    #pragma unroll
    for (int nt = 0; nt < 4; ++nt){
      int n = wave*64 + nt*16 + lr;
      int hh = n>>5, d = n&31;
      if (w == 2){
        // transposed V: rows rbase..rbase+3 contiguous -> packed 8B store
        uint32_t lo = cvt_pk_bf16(acc[mt][nt][0], acc[mt][nt][1]);
        uint32_t hi = cvt_pk_bf16(acc[mt][nt][2], acc[mt][nt][3]);
        *reinterpret_cast<uint2*>(&v[(((size_t)s*8 + hh)*32 + d)*384 + rbase]) = make_uint2(lo, hi);
      } else if (w == 1){
        #pragma unroll
        for (int t = 0; t < 4; ++t)
          k[(((size_t)s*8 + hh)*384 + rho_of(rbase + t))*32 + d] = f2bf(acc[mt][nt][t]);
      } else {
        ushort* out = (w==0) ? q : g;
        size_t o = (((size_t)s*8 + hh)*384 + rbase)*32 + d;
        #pragma unroll
        for (int t = 0; t < 4; ++t){
          float val = acc[mt][nt][t];
          if (w == 3) val = 1.0f/(1.0f + __expf(-(val + bg[n])));
          out[o + (size_t)t*32] = f2bf(val);
        }
      }
    }
  }
}

// ---------------- 5. attention v3: K direct-global (permuted), V^T LDS, exp2+cvt_pk ----
#define VSTR 392
__global__ __launch_bounds__(512, 8) void attn_kernel(const ushort* __restrict__ q,
    const ushort* __restrict__ kk, const ushort* __restrict__ vt, const ushort* __restrict__ gg,
    const float* __restrict__ bias, ushort* __restrict__ att_out){
  __shared__ ushort Vt[32*VSTR];
  const float SC2 = 0.17677669529663687f * 1.4426950408889634f;  // 1/sqrt(32) * log2e
  int s = blockIdx.x, h = blockIdx.y, tid = threadIdx.x;
  const size_t base = ((size_t)s*8 + h)*384*32;
  // stage V^T [d][r] -> LDS stride 392 (b128 copies, conflict-free)
  const ushort* vsrc = vt + base;
  #pragma unroll
  for (int it = 0; it < 3; ++it){
    int c = tid + it*512;                // 1536 chunks of 16B
    int d = c/48, rem = c - d*48;
    s16x8 val = *reinterpret_cast<const s16x8*>(vsrc + (size_t)d*384 + rem*8);
    *reinterpret_cast<s16x8*>(&Vt[d*VSTR + rem*8]) = val;
  }
  __syncthreads();
  int wave = tid>>6, lane = tid&63, lr = lane&15, lg = lane>>4;
  for (int itile = wave; itile < 24; itile += 8){
    int i0 = itile*16;
    s16x8 qf = *reinterpret_cast<const s16x8*>(q + base + (size_t)(i0 + lr)*32 + lg*8);
    const float* bp = bias + (size_t)h*147456 + (size_t)(i0 + lr)*384 + 8*lg;
    const ushort* kp = kk + base + (size_t)lr*32 + lg*8;   // permuted-rho K rows
    f32x4 acc0 = {0.f,0.f,0.f,0.f}, acc1 = {0.f,0.f,0.f,0.f};
    float rsA = 0.f, rsB = 0.f;
    #pragma unroll 4
    for (int m = 0; m < 12; ++m){
      s16x8 kf0 = *reinterpret_cast<const s16x8*>(kp + (size_t)(2*m+0)*512);
      s16x8 kf1 = *reinterpret_cast<const s16x8*>(kp + (size_t)(2*m+1)*512);
      f32x4 d0 = __builtin_amdgcn_mfma_f32_16x16x32_bf16(kf0, qf, (f32x4){0.f,0.f,0.f,0.f}, 0, 0, 0);
      f32x4 d1 = __builtin_amdgcn_mfma_f32_16x16x32_bf16(kf1, qf, (f32x4){0.f,0.f,0.f,0.f}, 0, 0, 0);
      f32x4 bv0 = *reinterpret_cast<const f32x4*>(bp + 32*m);
      f32x4 bv1 = *reinterpret_cast<const f32x4*>(bp + 32*m + 4);
      float e00 = exp2_fast(fmaf(d0[0], SC2, bv0[0]));
      float e01 = exp2_fast(fmaf(d0[1], SC2, bv0[1]));
      float e02 = exp2_fast(fmaf(d0[2], SC2, bv0[2]));
      float e03 = exp2_fast(fmaf(d0[3], SC2, bv0[3]));
      float e10 = exp2_fast(fmaf(d1[0], SC2, bv1[0]));
      float e11 = exp2_fast(fmaf(d1[1], SC2, bv1[1]));
      float e12 = exp2_fast(fmaf(d1[2], SC2, bv1[2]));
      float e13 = exp2_fast(fmaf(d1[3], SC2, bv1[3]));
      rsA += (e00 + e01) + (e02 + e03);
      rsB += (e10 + e11) + (e12 + e13);
      union { uint32_t u[4]; s16x8 v; } pa;
      pa.u[0] = cvt_pk_bf16(e00, e01);
      pa.u[1] = cvt_pk_bf16(e02, e03);
      pa.u[2] = cvt_pk_bf16(e10, e11);
      pa.u[3] = cvt_pk_bf16(e12, e13);
      s16x8 vb0 = *reinterpret_cast<const s16x8*>(&Vt[lr*VSTR + 32*m + 8*lg]);
      s16x8 vb1 = *reinterpret_cast<const s16x8*>(&Vt[(16+lr)*VSTR + 32*m + 8*lg]);
      acc0 = __builtin_amdgcn_mfma_f32_16x16x32_bf16(pa.v, vb0, acc0, 0, 0, 0);
      acc1 = __builtin_amdgcn_mfma_f32_16x16x32_bf16(pa.v, vb1, acc1, 0, 0, 0);
    }
    float rsum = rsA + rsB;
    rsum += __shfl_xor(rsum, 16);
    rsum += __shfl_xor(rsum, 32);
    const ushort* gp = gg + base + (size_t)(i0 + lg*4)*32;
    ushort* op = att_out + ((size_t)s*384 + i0 + lg*4)*256 + h*32;
    #pragma unroll
    for (int t = 0; t < 4; ++t){
      float inv = 1.0f / __shfl(rsum, 4*lg + t);
      float g0 = bf2f(gp[(size_t)t*32 + lr]);
      float g1 = bf2f(gp[(size_t)t*32 + 16 + lr]);
      op[(size_t)t*256 + lr]      = f2bf(acc0[t]*inv*g0);
      op[(size_t)t*256 + 16 + lr] = f2bf(acc1[t]*inv*g1);
    }
  }
}

// ---------------- 6. output projection ----------------
__global__ __launch_bounds__(256, 4) void oproj_kernel(const ushort* __restrict__ att,
    const ushort* __restrict__ Wot, const float* __restrict__ bo, float* __restrict__ out){
  __shared__ ushort Al[64*256];
  int tid = threadIdx.x, wave = tid>>6, lane = tid&63, lr = lane&15, lg = lane>>4;
  int m0 = blockIdx.x*64;
  stage_a64(att, m0, Al, tid);
  __syncthreads();
  f32x4 acc[4][4];
  #pragma unroll
  for (int a=0;a<4;++a) for (int b=0;b<4;++b) acc[a][b] = (f32x4){0.f,0.f,0.f,0.f};
  gemm64_lds(Al, Wot + (size_t)(wave*64)*256, lr, lg, acc);
  #pragma unroll
  for (int mt = 0; mt < 4; ++mt){
    int mrow = m0 + mt*16 + lg*4;
    #pragma unroll
    for (int nt = 0; nt < 4; ++nt){
      int n = wave*64 + nt*16 + lr;
      float bn = bo[n];
      #pragma unroll
      for (int t = 0; t < 4; ++t)
        out[(size_t)(mrow + t)*256 + n] = acc[mt][nt][t] + bn;
    }
  }
}

extern "C" void kernel_launch(void* const* d_in, const int* in_sizes, int n_in,
                              void* d_out, int out_size, void* d_ws, size_t ws_size,
                              hipStream_t stream){
  const float* msa  = (const float*)d_in[0];
  const float* pair = (const float*)d_in[1];
  const float* ln_g = (const float*)d_in[2];
  const float* ln_b = (const float*)d_in[3];
  const float* Wq   = (const float*)d_in[4];
  const float* Wk   = (const float*)d_in[5];
  const float* Wv   = (const float*)d_in[6];
  const float* Wb   = (const float*)d_in[7];
  const float* bb   = (const float*)d_in[8];
  const float* Wg   = (const float*)d_in[9];
  const float* bg   = (const float*)d_in[10];
  const float* Wo   = (const float*)d_in[11];
  const float* bo   = (const float*)d_in[12];
  float* out = (float*)d_out;
  char* ws = (char*)d_ws;
  const size_t SZ = (size_t)49152*256*2;            // 25,165,824 B per bf16 tensor
  ushort* xbf = (ushort*)(ws);
  ushort* qb  = (ushort*)(ws + SZ);
  ushort* kb  = (ushort*)(ws + 2*SZ);
  ushort* vb  = (ushort*)(ws + 3*SZ);
  ushort* gb  = (ushort*)(ws + 4*SZ);
  float*  bias= (float*)(ws + 5*SZ);                // 4,718,592 B
  ushort* wt  = (ushort*)(ws + 5*SZ + 4718592);     // 655,360 B
  ushort* att = xbf;                                 // reuse x buffer (dead after proj)
  float* part  = (float*)(ws + SZ);                  // LN scratch in qb region
  float* stats = (float*)(ws + SZ + 4*1024*1024);

  ln_part  <<<dim3(128,8),  dim3(256), 0, stream>>>(msa, part);
  ln_stats <<<dim3(128),    dim3(256), 0, stream>>>(part, stats);
  ln_apply <<<dim3(128,8),  dim3(256), 0, stream>>>(msa, stats, ln_g, ln_b, xbf);
  cvt_w      <<<dim3(256,5),   dim3(256), 0, stream>>>(Wq, Wk, Wv, Wg, Wo, wt);
  bias_kernel<<<dim3(384,12),  dim3(256), 0, stream>>>(pair, Wb, bb, bias);
  proj_kernel<<<dim3(768,4),   dim3(256), 0, stream>>>(xbf, wt, bg, qb, kb, vb, gb);
  attn_kernel<<<dim3(128,8),   dim3(512), 0, stream>>>(qb, kb, vb, gb, bias, att);
  oproj_kernel<<<dim3(768),    dim3(256), 0, stream>>>(att, wt + (size_t)4*65536, bo, out);
}